// Round 2
// baseline (174.701 us; speedup 1.0000x reference)
//
#include <hip/hip_runtime.h>
#include <math.h>

#define P 7
#define C 256
#define H 64
#define W 64

__global__ __launch_bounds__(256) void roi_pool_kernel(
    const float* __restrict__ features,
    const float* __restrict__ rois,
    float* __restrict__ out)
{
    const int rb = blockIdx.x;
    const int r = rb / P;      // roi index
    const int i = rb % P;      // row bin (H axis)
    const int c = threadIdx.x; // channel

    // --- decode roi (same for all threads in block; cheap scalar work) ---
    const float* roi = rois + r * 5;
    const int b  = (int)roi[0];
    // jnp.round is half-to-even; rintf matches (default RNE). The *1/32
    // scale is a power of two -> exact in f32, so rounding decisions match.
    int x0 = (int)rintf(roi[1] * 0.03125f);
    int y0 = (int)rintf(roi[2] * 0.03125f);
    int x1 = (int)rintf(roi[3] * 0.03125f);
    int y1 = (int)rintf(roi[4] * 0.03125f);
    x0 = min(max(x0, 0), W - 1);
    y0 = min(max(y0, 0), H - 1);
    x1 = min(max(x1, 0), W - 1);
    y1 = min(max(y1, 0), H - 1);

    const bool valid = (x0 < x1) && (y0 < y1);

    float* o = out + (((size_t)r * C + c) * P + i) * P;

    if (!valid) {
        // degenerate roi -> zeros (reference inits with zeros)
        #pragma unroll
        for (int j = 0; j < P; ++j) o[j] = 0.0f;
        return;
    }

    const int Lh = x1 - x0;  // x-range bins the H axis (reference quirk)
    const int Lw = y1 - y0;  // y-range bins the W axis

    // row bin i over H: [hs, he)
    const int hs = x0 + (i * Lh) / P;
    const int he = x0 + ((i + 1) * Lh + (P - 1)) / P;

    // col bins j over W: [ws[j], we[j])
    int ws[P], we[P];
    #pragma unroll
    for (int j = 0; j < P; ++j) {
        ws[j] = y0 + (j * Lw) / P;
        we[j] = y0 + ((j + 1) * Lw + (P - 1)) / P;
    }

    float acc[P];
    #pragma unroll
    for (int j = 0; j < P; ++j) acc[j] = -INFINITY;

    const float* f = features + (((size_t)b * C + c) * H) * W;

    for (int h = hs; h < he; ++h) {
        const float* row = f + h * W;
        #pragma unroll
        for (int j = 0; j < P; ++j) {
            float m = acc[j];
            for (int w = ws[j]; w < we[j]; ++w) {
                m = fmaxf(m, row[w]);
            }
            acc[j] = m;
        }
    }

    #pragma unroll
    for (int j = 0; j < P; ++j) o[j] = acc[j];
}

extern "C" void kernel_launch(void* const* d_in, const int* in_sizes, int n_in,
                              void* d_out, int out_size, void* d_ws, size_t ws_size,
                              hipStream_t stream)
{
    const float* features = (const float*)d_in[0];
    const float* rois     = (const float*)d_in[1];
    float* out = (float*)d_out;

    const int R = in_sizes[1] / 5;   // 256 rois
    dim3 grid(R * P);
    dim3 block(C);
    roi_pool_kernel<<<grid, block, 0, stream>>>(features, rois, out);
}

// Round 3
// 124.056 us; speedup vs baseline: 1.4083x; 1.4083x over previous
//
#include <hip/hip_runtime.h>
#include <math.h>

#define P 7
#define C 256
#define H 64
#define W 64
#define S (H * W)

// ---------------------------------------------------------------------------
// Transpose [N, C, S] -> [N, S, C], tiled 32x32 through LDS, coalesced both ways
// ---------------------------------------------------------------------------
#define TS 32
__global__ __launch_bounds__(256) void transpose_kernel(
    const float* __restrict__ in, float* __restrict__ outT)
{
    __shared__ float tile[TS][TS + 1];
    const int b  = blockIdx.z;
    const int s0 = blockIdx.x * TS;
    const int c0 = blockIdx.y * TS;
    const int tx = threadIdx.x;  // 0..31
    const int ty = threadIdx.y;  // 0..7

    const float* ip = in + ((size_t)b * C + c0) * S + s0;
    #pragma unroll
    for (int k = 0; k < 4; ++k)
        tile[ty + 8 * k][tx] = ip[(size_t)(ty + 8 * k) * S + tx];

    __syncthreads();

    float* op = outT + ((size_t)b * S + s0) * C + c0;
    #pragma unroll
    for (int k = 0; k < 4; ++k)
        op[(size_t)(ty + 8 * k) * C + tx] = tile[tx][ty + 8 * k];
}

// ---------------------------------------------------------------------------
// RoI max-pool on transposed features [N, H, W, C]; lane = channel pair
// (fully coalesced: 64 lanes x 8B = 512B contiguous per wave-load)
// ---------------------------------------------------------------------------
__global__ __launch_bounds__(128) void roi_pool_t_kernel(
    const float* __restrict__ ft,    // [N, H, W, C]
    const float* __restrict__ rois,
    float* __restrict__ out)         // [R, C, P, P]
{
    const int rb = blockIdx.x;
    const int r  = rb / P;       // roi index
    const int i  = rb % P;       // row bin (H axis)
    const int c  = threadIdx.x * 2;  // channel pair base

    const float* roi = rois + r * 5;
    const int b = (int)roi[0];
    // jnp.round is half-to-even; rintf matches (RNE); *2^-5 scale is exact.
    int x0 = (int)rintf(roi[1] * 0.03125f);
    int y0 = (int)rintf(roi[2] * 0.03125f);
    int x1 = (int)rintf(roi[3] * 0.03125f);
    int y1 = (int)rintf(roi[4] * 0.03125f);
    x0 = min(max(x0, 0), W - 1);
    y0 = min(max(y0, 0), H - 1);
    x1 = min(max(x1, 0), W - 1);
    y1 = min(max(y1, 0), H - 1);

    const bool valid = (x0 < x1) && (y0 < y1);

    float* o0 = out + (((size_t)r * C + c) * P + i) * P;
    float* o1 = o0 + P * P;

    if (!valid) {
        #pragma unroll
        for (int j = 0; j < P; ++j) { o0[j] = 0.0f; o1[j] = 0.0f; }
        return;
    }

    const int Lh = x1 - x0;  // x-range bins the H axis (reference quirk)
    const int Lw = y1 - y0;  // y-range bins the W axis

    const int hs = x0 + (i * Lh) / P;
    const int he = x0 + ((i + 1) * Lh + (P - 1)) / P;

    int ws_[P], we_[P];
    #pragma unroll
    for (int j = 0; j < P; ++j) {
        ws_[j] = y0 + (j * Lw) / P;
        we_[j] = y0 + ((j + 1) * Lw + (P - 1)) / P;
    }

    float2 acc[P];
    #pragma unroll
    for (int j = 0; j < P; ++j) acc[j] = make_float2(-INFINITY, -INFINITY);

    const float* fb = ft + ((size_t)b * H) * W * C + c;

    for (int h = hs; h < he; ++h) {
        const float* row = fb + (size_t)h * W * C;
        #pragma unroll
        for (int j = 0; j < P; ++j) {
            float mx = acc[j].x, my = acc[j].y;
            for (int w = ws_[j]; w < we_[j]; ++w) {
                const float2 v = *(const float2*)(row + (size_t)w * C);
                mx = fmaxf(mx, v.x);
                my = fmaxf(my, v.y);
            }
            acc[j].x = mx; acc[j].y = my;
        }
    }

    #pragma unroll
    for (int j = 0; j < P; ++j) { o0[j] = acc[j].x; o1[j] = acc[j].y; }
}

// ---------------------------------------------------------------------------
// Fallback (round-1 kernel, strided reads) if workspace is too small
// ---------------------------------------------------------------------------
__global__ __launch_bounds__(256) void roi_pool_kernel(
    const float* __restrict__ features,
    const float* __restrict__ rois,
    float* __restrict__ out)
{
    const int rb = blockIdx.x;
    const int r = rb / P;
    const int i = rb % P;
    const int c = threadIdx.x;

    const float* roi = rois + r * 5;
    const int b = (int)roi[0];
    int x0 = (int)rintf(roi[1] * 0.03125f);
    int y0 = (int)rintf(roi[2] * 0.03125f);
    int x1 = (int)rintf(roi[3] * 0.03125f);
    int y1 = (int)rintf(roi[4] * 0.03125f);
    x0 = min(max(x0, 0), W - 1);
    y0 = min(max(y0, 0), H - 1);
    x1 = min(max(x1, 0), W - 1);
    y1 = min(max(y1, 0), H - 1);

    const bool valid = (x0 < x1) && (y0 < y1);
    float* o = out + (((size_t)r * C + c) * P + i) * P;

    if (!valid) {
        #pragma unroll
        for (int j = 0; j < P; ++j) o[j] = 0.0f;
        return;
    }

    const int Lh = x1 - x0;
    const int Lw = y1 - y0;
    const int hs = x0 + (i * Lh) / P;
    const int he = x0 + ((i + 1) * Lh + (P - 1)) / P;

    int ws_[P], we_[P];
    #pragma unroll
    for (int j = 0; j < P; ++j) {
        ws_[j] = y0 + (j * Lw) / P;
        we_[j] = y0 + ((j + 1) * Lw + (P - 1)) / P;
    }

    float acc[P];
    #pragma unroll
    for (int j = 0; j < P; ++j) acc[j] = -INFINITY;

    const float* f = features + (((size_t)b * C + c) * H) * W;
    for (int h = hs; h < he; ++h) {
        const float* row = f + h * W;
        #pragma unroll
        for (int j = 0; j < P; ++j) {
            float m = acc[j];
            for (int w = ws_[j]; w < we_[j]; ++w) m = fmaxf(m, row[w]);
            acc[j] = m;
        }
    }
    #pragma unroll
    for (int j = 0; j < P; ++j) o[j] = acc[j];
}

extern "C" void kernel_launch(void* const* d_in, const int* in_sizes, int n_in,
                              void* d_out, int out_size, void* d_ws, size_t ws_size,
                              hipStream_t stream)
{
    const float* features = (const float*)d_in[0];
    const float* rois     = (const float*)d_in[1];
    float* out = (float*)d_out;

    const int R = in_sizes[1] / 5;                  // 256 rois
    const int N = in_sizes[0] / (C * S);            // 4 images
    const size_t needed = (size_t)N * C * S * sizeof(float);  // 16 MB

    if (ws_size >= needed) {
        float* ft = (float*)d_ws;
        dim3 tgrid(S / TS, C / TS, N);
        dim3 tblock(TS, 8);
        transpose_kernel<<<tgrid, tblock, 0, stream>>>(features, ft);

        dim3 grid(R * P);
        dim3 block(C / 2);
        roi_pool_t_kernel<<<grid, block, 0, stream>>>(ft, rois, out);
    } else {
        dim3 grid(R * P);
        dim3 block(C);
        roi_pool_kernel<<<grid, block, 0, stream>>>(features, rois, out);
    }
}

// Round 4
// 70.094 us; speedup vs baseline: 2.4924x; 1.7698x over previous
//
#include <hip/hip_runtime.h>
#include <math.h>

#define P 7
#define C 256
#define H 64
#define W 64
#define S (H * W)

// ---------------------------------------------------------------------------
// Transpose [N, C, S] -> [N, S, C], tiled 32x32 through LDS, coalesced both ways
// ---------------------------------------------------------------------------
#define TS 32
__global__ __launch_bounds__(256) void transpose_kernel(
    const float* __restrict__ in, float* __restrict__ outT)
{
    __shared__ float tile[TS][TS + 1];
    const int b  = blockIdx.z;
    const int s0 = blockIdx.x * TS;
    const int c0 = blockIdx.y * TS;
    const int tx = threadIdx.x;  // 0..31
    const int ty = threadIdx.y;  // 0..7

    const float* ip = in + ((size_t)b * C + c0) * S + s0;
    #pragma unroll
    for (int k = 0; k < 4; ++k)
        tile[ty + 8 * k][tx] = ip[(size_t)(ty + 8 * k) * S + tx];

    __syncthreads();

    float* op = outT + ((size_t)b * S + s0) * C + c0;
    #pragma unroll
    for (int k = 0; k < 4; ++k)
        op[(size_t)(ty + 8 * k) * C + tx] = tile[tx][ty + 8 * k];
}

// ---------------------------------------------------------------------------
// RoI max-pool, one 64-thread block per output cell (r, i, j).
// Lane = 4-channel group (float4): 64 lanes x 16B = 1KB coalesced wave-load.
// 2x2 batched inner loop with clamped (idempotent) edges -> 4 independent
// loads in flight per iteration, no remainder code.
// ---------------------------------------------------------------------------
__global__ __launch_bounds__(64) void roi_pool_cell_kernel(
    const float* __restrict__ ft,    // [N, H, W, C]
    const float* __restrict__ rois,
    float* __restrict__ out)         // [R, C, P, P]
{
    const int bid = blockIdx.x;
    const int r   = bid / (P * P);
    const int rem = bid % (P * P);
    const int i   = rem / P;         // row bin (H axis)
    const int j   = rem % P;         // col bin (W axis)
    const int c4  = threadIdx.x;     // channel quad: channels 4*c4 .. 4*c4+3

    const float* roi = rois + r * 5;
    const int b = (int)roi[0];
    // jnp.round is half-to-even; rintf matches (RNE); *2^-5 scale is exact.
    int x0 = (int)rintf(roi[1] * 0.03125f);
    int y0 = (int)rintf(roi[2] * 0.03125f);
    int x1 = (int)rintf(roi[3] * 0.03125f);
    int y1 = (int)rintf(roi[4] * 0.03125f);
    x0 = min(max(x0, 0), W - 1);
    y0 = min(max(y0, 0), H - 1);
    x1 = min(max(x1, 0), W - 1);
    y1 = min(max(y1, 0), H - 1);

    float* o = out + (((size_t)r * C + c4 * 4) * P + i) * P + j;

    if (!((x0 < x1) && (y0 < y1))) {
        o[0] = 0.0f; o[P * P] = 0.0f; o[2 * P * P] = 0.0f; o[3 * P * P] = 0.0f;
        return;
    }

    const int Lh = x1 - x0;  // x-range bins the H axis (reference quirk)
    const int Lw = y1 - y0;  // y-range bins the W axis

    const int hs = x0 + (i * Lh) / P;
    const int he = x0 + ((i + 1) * Lh + (P - 1)) / P;
    const int ws = y0 + (j * Lw) / P;
    const int we = y0 + ((j + 1) * Lw + (P - 1)) / P;

    const int bh = he - hs;          // >= 1 for valid rois
    const int bw = we - ws;          // >= 1

    const float* base = ft + (((size_t)b * H + hs) * W + ws) * C + c4 * 4;

    float mx = -INFINITY, my = -INFINITY, mz = -INFINITY, mw = -INFINITY;

    for (int h = 0; h < bh; h += 2) {
        const int h2 = min(h + 1, bh - 1);      // clamp: duplicate row is a no-op for max
        const float* r0 = base + (size_t)h  * (W * C);
        const float* r1 = base + (size_t)h2 * (W * C);
        for (int w = 0; w < bw; w += 2) {
            const int w2 = min(w + 1, bw - 1);  // clamp: duplicate col is a no-op for max
            const float4 a = *(const float4*)(r0 + (size_t)w  * C);
            const float4 bb = *(const float4*)(r0 + (size_t)w2 * C);
            const float4 cc = *(const float4*)(r1 + (size_t)w  * C);
            const float4 dd = *(const float4*)(r1 + (size_t)w2 * C);
            mx = fmaxf(fmaxf(fmaxf(mx, a.x), fmaxf(bb.x, cc.x)), dd.x);
            my = fmaxf(fmaxf(fmaxf(my, a.y), fmaxf(bb.y, cc.y)), dd.y);
            mz = fmaxf(fmaxf(fmaxf(mz, a.z), fmaxf(bb.z, cc.z)), dd.z);
            mw = fmaxf(fmaxf(fmaxf(mw, a.w), fmaxf(bb.w, cc.w)), dd.w);
        }
    }

    o[0] = mx; o[P * P] = my; o[2 * P * P] = mz; o[3 * P * P] = mw;
}

// ---------------------------------------------------------------------------
// Fallback (round-1 kernel, strided reads) if workspace is too small
// ---------------------------------------------------------------------------
__global__ __launch_bounds__(256) void roi_pool_kernel(
    const float* __restrict__ features,
    const float* __restrict__ rois,
    float* __restrict__ out)
{
    const int rb = blockIdx.x;
    const int r = rb / P;
    const int i = rb % P;
    const int c = threadIdx.x;

    const float* roi = rois + r * 5;
    const int b = (int)roi[0];
    int x0 = (int)rintf(roi[1] * 0.03125f);
    int y0 = (int)rintf(roi[2] * 0.03125f);
    int x1 = (int)rintf(roi[3] * 0.03125f);
    int y1 = (int)rintf(roi[4] * 0.03125f);
    x0 = min(max(x0, 0), W - 1);
    y0 = min(max(y0, 0), H - 1);
    x1 = min(max(x1, 0), W - 1);
    y1 = min(max(y1, 0), H - 1);

    const bool valid = (x0 < x1) && (y0 < y1);
    float* o = out + (((size_t)r * C + c) * P + i) * P;

    if (!valid) {
        #pragma unroll
        for (int j = 0; j < P; ++j) o[j] = 0.0f;
        return;
    }

    const int Lh = x1 - x0;
    const int Lw = y1 - y0;
    const int hs = x0 + (i * Lh) / P;
    const int he = x0 + ((i + 1) * Lh + (P - 1)) / P;

    int ws_[P], we_[P];
    #pragma unroll
    for (int j = 0; j < P; ++j) {
        ws_[j] = y0 + (j * Lw) / P;
        we_[j] = y0 + ((j + 1) * Lw + (P - 1)) / P;
    }

    float acc[P];
    #pragma unroll
    for (int j = 0; j < P; ++j) acc[j] = -INFINITY;

    const float* f = features + (((size_t)b * C + c) * H) * W;
    for (int h = hs; h < he; ++h) {
        const float* row = f + h * W;
        #pragma unroll
        for (int j = 0; j < P; ++j) {
            float m = acc[j];
            for (int w = ws_[j]; w < we_[j]; ++w) m = fmaxf(m, row[w]);
            acc[j] = m;
        }
    }
    #pragma unroll
    for (int j = 0; j < P; ++j) o[j] = acc[j];
}

extern "C" void kernel_launch(void* const* d_in, const int* in_sizes, int n_in,
                              void* d_out, int out_size, void* d_ws, size_t ws_size,
                              hipStream_t stream)
{
    const float* features = (const float*)d_in[0];
    const float* rois     = (const float*)d_in[1];
    float* out = (float*)d_out;

    const int R = in_sizes[1] / 5;                  // 256 rois
    const int N = in_sizes[0] / (C * S);            // 4 images
    const size_t needed = (size_t)N * C * S * sizeof(float);  // 16 MB

    if (ws_size >= needed) {
        float* ft = (float*)d_ws;
        dim3 tgrid(S / TS, C / TS, N);
        dim3 tblock(TS, 8);
        transpose_kernel<<<tgrid, tblock, 0, stream>>>(features, ft);

        dim3 grid(R * P * P);
        dim3 block(64);
        roi_pool_cell_kernel<<<grid, block, 0, stream>>>(ft, rois, out);
    } else {
        dim3 grid(R * P);
        dim3 block(C);
        roi_pool_kernel<<<grid, block, 0, stream>>>(features, rois, out);
    }
}

// Round 5
// 41.847 us; speedup vs baseline: 4.1748x; 1.6750x over previous
//
#include <hip/hip_runtime.h>
#include <math.h>

#define P 7
#define PP (P * P)
#define C 256
#define H 64
#define W 64
#define S (H * W)
#define R_MAX 1024

// ---------------------------------------------------------------------------
// Transpose [N, C, S] -> [N, S, C], tiled 32x32 through LDS
// ---------------------------------------------------------------------------
#define TS 32
__global__ __launch_bounds__(256) void transpose_kernel(
    const float* __restrict__ in, float* __restrict__ outT)
{
    __shared__ float tile[TS][TS + 1];
    const int b  = blockIdx.z;
    const int s0 = blockIdx.x * TS;
    const int c0 = blockIdx.y * TS;
    const int tx = threadIdx.x;  // 0..31
    const int ty = threadIdx.y;  // 0..7

    const float* ip = in + ((size_t)b * C + c0) * S + s0;
    #pragma unroll
    for (int k = 0; k < 4; ++k)
        tile[ty + 8 * k][tx] = ip[(size_t)(ty + 8 * k) * S + tx];

    __syncthreads();

    float* op = outT + ((size_t)b * S + s0) * C + c0;
    #pragma unroll
    for (int k = 0; k < 4; ++k)
        op[(size_t)(ty + 8 * k) * C + tx] = tile[tx][ty + 8 * k];
}

// ---------------------------------------------------------------------------
// Stable counting-sort of rois by image id -> perm (deterministic, ~1us)
// perm[pos] = roi index; rois of the same image end up contiguous.
// ---------------------------------------------------------------------------
__global__ __launch_bounds__(256) void bucket_kernel(
    const float* __restrict__ rois, int* __restrict__ perm, int R)
{
    __shared__ int bimg[R_MAX];
    for (int t = threadIdx.x; t < R; t += blockDim.x)
        bimg[t] = (int)rois[(size_t)t * 5];
    __syncthreads();
    for (int t = threadIdx.x; t < R; t += blockDim.x) {
        const int myb = bimg[t];
        int pos = 0;
        for (int k = 0; k < R; ++k) {
            const int bk = bimg[k];
            pos += (bk < myb) || (bk == myb && k < t);
        }
        perm[pos] = t;
    }
}

// ---------------------------------------------------------------------------
// RoI max-pool, one 64-thread block per (rslot, cell). Reads [N,H,W,C],
// writes ws2[rslot, cell, C] as one contiguous 1KB wave-store (float4/lane).
// Chunked XCD swizzle keeps one roi's 49 cells (and ~one image) per XCD L2.
// ---------------------------------------------------------------------------
__global__ __launch_bounds__(64) void roi_pool_cell_kernel(
    const float* __restrict__ ft,    // [N, H, W, C]
    const float* __restrict__ rois,
    const int*   __restrict__ perm,
    float* __restrict__ ws2)         // [R, PP, C]
{
    const int l   = blockIdx.x;
    const int nwg = gridDim.x;
    const int work = ((nwg & 7) == 0) ? ((l & 7) * (nwg >> 3) + (l >> 3)) : l;

    const int rslot = work / PP;
    const int cell  = work % PP;
    const int i     = cell / P;      // row bin (H axis)
    const int j     = cell % P;      // col bin (W axis)
    const int c4    = threadIdx.x;   // channel quad

    const int r = perm[rslot];

    const float* roi = rois + (size_t)r * 5;
    const int b = (int)roi[0];
    // jnp.round is half-to-even; rintf matches (RNE); *2^-5 scale is exact.
    int x0 = (int)rintf(roi[1] * 0.03125f);
    int y0 = (int)rintf(roi[2] * 0.03125f);
    int x1 = (int)rintf(roi[3] * 0.03125f);
    int y1 = (int)rintf(roi[4] * 0.03125f);
    x0 = min(max(x0, 0), W - 1);
    y0 = min(max(y0, 0), H - 1);
    x1 = min(max(x1, 0), W - 1);
    y1 = min(max(y1, 0), H - 1);

    float4* o = (float4*)(ws2 + ((size_t)rslot * PP + cell) * C) + c4;

    if (!((x0 < x1) && (y0 < y1))) {
        *o = make_float4(0.0f, 0.0f, 0.0f, 0.0f);
        return;
    }

    const int Lh = x1 - x0;  // x-range bins the H axis (reference quirk)
    const int Lw = y1 - y0;  // y-range bins the W axis

    const int hs = x0 + (i * Lh) / P;
    const int he = x0 + ((i + 1) * Lh + (P - 1)) / P;
    const int ws = y0 + (j * Lw) / P;
    const int we = y0 + ((j + 1) * Lw + (P - 1)) / P;

    const int bh = he - hs;
    const int bw = we - ws;

    const float* base = ft + (((size_t)b * H + hs) * W + ws) * C + c4 * 4;

    float mx = -INFINITY, my = -INFINITY, mz = -INFINITY, mw = -INFINITY;

    for (int h = 0; h < bh; h += 2) {
        const int h2 = min(h + 1, bh - 1);      // clamp: dup row is a no-op for max
        const float* r0 = base + (size_t)h  * (W * C);
        const float* r1 = base + (size_t)h2 * (W * C);
        for (int w = 0; w < bw; w += 2) {
            const int w2 = min(w + 1, bw - 1);  // clamp: dup col is a no-op for max
            const float4 a  = *(const float4*)(r0 + (size_t)w  * C);
            const float4 bb = *(const float4*)(r0 + (size_t)w2 * C);
            const float4 cc = *(const float4*)(r1 + (size_t)w  * C);
            const float4 dd = *(const float4*)(r1 + (size_t)w2 * C);
            mx = fmaxf(fmaxf(fmaxf(mx, a.x), fmaxf(bb.x, cc.x)), dd.x);
            my = fmaxf(fmaxf(fmaxf(my, a.y), fmaxf(bb.y, cc.y)), dd.y);
            mz = fmaxf(fmaxf(fmaxf(mz, a.z), fmaxf(bb.z, cc.z)), dd.z);
            mw = fmaxf(fmaxf(fmaxf(mw, a.w), fmaxf(bb.w, cc.w)), dd.w);
        }
    }

    *o = make_float4(mx, my, mz, mw);
}

// ---------------------------------------------------------------------------
// Reorder ws2[rslot, cell, C] -> out[r, C, cell] via LDS; both sides
// coalesced, out written as full-line float4 stores.
// ---------------------------------------------------------------------------
#define LPAD 257
__global__ __launch_bounds__(256) void reorder_kernel(
    const float* __restrict__ ws2,
    const int*   __restrict__ perm,
    float* __restrict__ out)         // [R, C, PP]
{
    __shared__ float lds[PP * LPAD];
    const int l = blockIdx.x;
    const int R = gridDim.x;
    const int rslot = ((R & 7) == 0) ? ((l & 7) * (R >> 3) + (l >> 3)) : l;
    const int r = perm[rslot];
    const int tid = threadIdx.x;

    const float* src = ws2 + (size_t)rslot * PP * C;
    #pragma unroll
    for (int cell = 0; cell < PP; ++cell)
        lds[cell * LPAD + tid] = src[(size_t)cell * C + tid];

    __syncthreads();

    float* dst = out + (size_t)r * C * PP;
    const int nq = (C * PP) / 4;     // 3136 float4s
    #pragma unroll
    for (int k = 0; k < 13; ++k) {
        const int q = tid + 256 * k;
        if (q < nq) {
            float v[4];
            #pragma unroll
            for (int m = 0; m < 4; ++m) {
                const int idx  = 4 * q + m;
                const int c    = idx / PP;
                const int cell = idx % PP;
                v[m] = lds[cell * LPAD + c];
            }
            *(float4*)(dst + 4 * q) = make_float4(v[0], v[1], v[2], v[3]);
        }
    }
}

// ---------------------------------------------------------------------------
// Fallback tier 1 (round-4 path): pool with direct strided out writes
// ---------------------------------------------------------------------------
__global__ __launch_bounds__(64) void roi_pool_cell_direct_kernel(
    const float* __restrict__ ft, const float* __restrict__ rois,
    float* __restrict__ out)
{
    const int bid = blockIdx.x;
    const int r   = bid / PP;
    const int rem = bid % PP;
    const int i   = rem / P;
    const int j   = rem % P;
    const int c4  = threadIdx.x;

    const float* roi = rois + (size_t)r * 5;
    const int b = (int)roi[0];
    int x0 = (int)rintf(roi[1] * 0.03125f);
    int y0 = (int)rintf(roi[2] * 0.03125f);
    int x1 = (int)rintf(roi[3] * 0.03125f);
    int y1 = (int)rintf(roi[4] * 0.03125f);
    x0 = min(max(x0, 0), W - 1);
    y0 = min(max(y0, 0), H - 1);
    x1 = min(max(x1, 0), W - 1);
    y1 = min(max(y1, 0), H - 1);

    float* o = out + (((size_t)r * C + c4 * 4) * P + i) * P + j;
    if (!((x0 < x1) && (y0 < y1))) {
        o[0] = 0.0f; o[PP] = 0.0f; o[2 * PP] = 0.0f; o[3 * PP] = 0.0f;
        return;
    }
    const int Lh = x1 - x0, Lw = y1 - y0;
    const int hs = x0 + (i * Lh) / P;
    const int he = x0 + ((i + 1) * Lh + (P - 1)) / P;
    const int ws = y0 + (j * Lw) / P;
    const int we = y0 + ((j + 1) * Lw + (P - 1)) / P;
    const int bh = he - hs, bw = we - ws;
    const float* base = ft + (((size_t)b * H + hs) * W + ws) * C + c4 * 4;
    float mx = -INFINITY, my = -INFINITY, mz = -INFINITY, mw = -INFINITY;
    for (int h = 0; h < bh; h += 2) {
        const int h2 = min(h + 1, bh - 1);
        const float* r0 = base + (size_t)h  * (W * C);
        const float* r1 = base + (size_t)h2 * (W * C);
        for (int w = 0; w < bw; w += 2) {
            const int w2 = min(w + 1, bw - 1);
            const float4 a  = *(const float4*)(r0 + (size_t)w  * C);
            const float4 bb = *(const float4*)(r0 + (size_t)w2 * C);
            const float4 cc = *(const float4*)(r1 + (size_t)w  * C);
            const float4 dd = *(const float4*)(r1 + (size_t)w2 * C);
            mx = fmaxf(fmaxf(fmaxf(mx, a.x), fmaxf(bb.x, cc.x)), dd.x);
            my = fmaxf(fmaxf(fmaxf(my, a.y), fmaxf(bb.y, cc.y)), dd.y);
            mz = fmaxf(fmaxf(fmaxf(mz, a.z), fmaxf(bb.z, cc.z)), dd.z);
            mw = fmaxf(fmaxf(fmaxf(mw, a.w), fmaxf(bb.w, cc.w)), dd.w);
        }
    }
    o[0] = mx; o[PP] = my; o[2 * PP] = mz; o[3 * PP] = mw;
}

// ---------------------------------------------------------------------------
// Fallback tier 2 (round-1 path): no workspace
// ---------------------------------------------------------------------------
__global__ __launch_bounds__(256) void roi_pool_naive_kernel(
    const float* __restrict__ features, const float* __restrict__ rois,
    float* __restrict__ out)
{
    const int rb = blockIdx.x;
    const int r = rb / P;
    const int i = rb % P;
    const int c = threadIdx.x;

    const float* roi = rois + (size_t)r * 5;
    const int b = (int)roi[0];
    int x0 = (int)rintf(roi[1] * 0.03125f);
    int y0 = (int)rintf(roi[2] * 0.03125f);
    int x1 = (int)rintf(roi[3] * 0.03125f);
    int y1 = (int)rintf(roi[4] * 0.03125f);
    x0 = min(max(x0, 0), W - 1);
    y0 = min(max(y0, 0), H - 1);
    x1 = min(max(x1, 0), W - 1);
    y1 = min(max(y1, 0), H - 1);

    const bool valid = (x0 < x1) && (y0 < y1);
    float* o = out + (((size_t)r * C + c) * P + i) * P;
    if (!valid) {
        #pragma unroll
        for (int j = 0; j < P; ++j) o[j] = 0.0f;
        return;
    }
    const int Lh = x1 - x0, Lw = y1 - y0;
    const int hs = x0 + (i * Lh) / P;
    const int he = x0 + ((i + 1) * Lh + (P - 1)) / P;
    int ws_[P], we_[P];
    #pragma unroll
    for (int j = 0; j < P; ++j) {
        ws_[j] = y0 + (j * Lw) / P;
        we_[j] = y0 + ((j + 1) * Lw + (P - 1)) / P;
    }
    float acc[P];
    #pragma unroll
    for (int j = 0; j < P; ++j) acc[j] = -INFINITY;
    const float* f = features + (((size_t)b * C + c) * H) * W;
    for (int h = hs; h < he; ++h) {
        const float* row = f + h * W;
        #pragma unroll
        for (int j = 0; j < P; ++j) {
            float m = acc[j];
            for (int w = ws_[j]; w < we_[j]; ++w) m = fmaxf(m, row[w]);
            acc[j] = m;
        }
    }
    #pragma unroll
    for (int j = 0; j < P; ++j) o[j] = acc[j];
}

extern "C" void kernel_launch(void* const* d_in, const int* in_sizes, int n_in,
                              void* d_out, int out_size, void* d_ws, size_t ws_size,
                              hipStream_t stream)
{
    const float* features = (const float*)d_in[0];
    const float* rois     = (const float*)d_in[1];
    float* out = (float*)d_out;

    const int R = in_sizes[1] / 5;                  // 256
    const int N = in_sizes[0] / (C * S);            // 4

    const size_t ft_bytes  = (size_t)N * C * S * sizeof(float);     // 16 MB
    const size_t ws2_bytes = (size_t)R * PP * C * sizeof(float);    // 12.8 MB
    const size_t perm_bytes = (size_t)R * sizeof(int);
    const size_t full_need = ft_bytes + ws2_bytes + perm_bytes;

    if (ws_size >= full_need && R <= R_MAX) {
        float* ft  = (float*)d_ws;
        float* ws2 = (float*)((char*)d_ws + ft_bytes);
        int*  perm = (int*)((char*)d_ws + ft_bytes + ws2_bytes);

        dim3 tgrid(S / TS, C / TS, N);
        transpose_kernel<<<tgrid, dim3(TS, 8), 0, stream>>>(features, ft);
        bucket_kernel<<<1, 256, 0, stream>>>(rois, perm, R);
        roi_pool_cell_kernel<<<R * PP, 64, 0, stream>>>(ft, rois, perm, ws2);
        reorder_kernel<<<R, 256, 0, stream>>>(ws2, perm, out);
    } else if (ws_size >= ft_bytes) {
        float* ft = (float*)d_ws;
        dim3 tgrid(S / TS, C / TS, N);
        transpose_kernel<<<tgrid, dim3(TS, 8), 0, stream>>>(features, ft);
        roi_pool_cell_direct_kernel<<<R * PP, 64, 0, stream>>>(ft, rois, out);
    } else {
        roi_pool_naive_kernel<<<R * P, C, 0, stream>>>(features, rois, out);
    }
}